// Round 3
// baseline (3127.791 us; speedup 1.0000x reference)
//
#include <hip/hip_runtime.h>

#define B_   128
#define T_   128
#define DIN  64
#define H_   1024
#define NBLK 256
#define NTHR 512

typedef _Float16 f16;
typedef _Float16 half8 __attribute__((ext_vector_type(8)));
typedef float float4v __attribute__((ext_vector_type(4)));

// LDS layout (dynamic shared), W in lane-ordered MFMA fragment layout:
//  W1s: f16[34][512]  chunk-major, within chunk lane*8 (16B/lane)   34816 B
//  W2s: f16[64][512]                                                65536 B
//  SgA: float[128][17] gate partials (K-half 0)                      8704 B
//  SgB: float[128][17] gate partials (K-half 1)                      8704 B
//  c1 : float[512], c2 : float[512]                                  4096 B
//  bs1: float[16], bs2: float[16]                                     128 B
#define OFF_W2  34816
#define OFF_SGA 100352
#define OFF_SGB 109056
#define OFF_C1  117760
#define OFF_C2  119808
#define OFF_B1  121856
#define OFF_B2  121920
#define SMEM_BYTES 121984

struct Params {
  const float *x, *Wih1, *Whh1, *bih1, *bhh1, *Wih2, *Whh2, *bih2, *bhh2,
              *Wlin, *blin, *Whio, *bhio;
  const int* fut;
  float* out;
  f16 *x16, *h1a, *h1b, *h2a, *h2b, *ob;
  unsigned *arrive, *rel;
  unsigned *S;   // [0..15] xtick, [16..31] xflag, [32] central, [33] release, [34..49] xtot
};

__device__ __forceinline__ float sigm(float v) { return 1.f / (1.f + __expf(-v)); }
__device__ __forceinline__ float tanh_(float v) { return 2.f / (1.f + __expf(-2.f * v)) - 1.f; }

__device__ __forceinline__ unsigned get_xcc() {
  unsigned x;
  asm volatile("s_getreg_b32 %0, hwreg(HW_REG_XCC_ID)" : "=s"(x));
  return x & 15u;
}

// ---- slow barrier (preamble only) -----------------------------------------
__device__ __forceinline__ void grid_sync(unsigned* arrive, unsigned* rel, unsigned ph) {
  __syncthreads();
  const int tid = threadIdx.x, bid = blockIdx.x;
  if (bid == 0) {
    if (tid > 0 && tid < NBLK) {
      while (__hip_atomic_load(&arrive[tid], __ATOMIC_RELAXED, __HIP_MEMORY_SCOPE_AGENT) != ph)
        __builtin_amdgcn_s_sleep(1);
    }
    __syncthreads();
    if (tid == 0)
      __hip_atomic_store(rel, ph, __ATOMIC_RELEASE, __HIP_MEMORY_SCOPE_AGENT);
  } else {
    if (tid == 0) {
      __hip_atomic_store(&arrive[bid], ph, __ATOMIC_RELEASE, __HIP_MEMORY_SCOPE_AGENT);
      while (__hip_atomic_load(rel, __ATOMIC_RELAXED, __HIP_MEMORY_SCOPE_AGENT) != ph)
        __builtin_amdgcn_s_sleep(1);
    }
  }
  __syncthreads();
  __builtin_amdgcn_fence(__ATOMIC_ACQUIRE, "agent");
}

// ---- fast barrier: ONE buffer_wbl2 + ONE buffer_inv (L2) per XCD per phase.
__device__ __forceinline__ void fast_sync(unsigned* S, unsigned x, unsigned xtotal,
                                          unsigned nxcd, unsigned ph) {
  __syncthreads();
  if (threadIdx.x == 0) {
    unsigned t = __hip_atomic_fetch_add(&S[x], 1u, __ATOMIC_RELAXED, __HIP_MEMORY_SCOPE_AGENT);
    if ((t + 1u) % xtotal == 0u) {            // last block of this XCD
      asm volatile("buffer_wbl2 sc1\n\ts_waitcnt vmcnt(0)" ::: "memory");
      unsigned c = __hip_atomic_fetch_add(&S[32], 1u, __ATOMIC_RELAXED, __HIP_MEMORY_SCOPE_AGENT);
      if ((c + 1u) % nxcd == 0u)              // last XCD globally -> release
        __hip_atomic_store(&S[33], ph, __ATOMIC_RELAXED, __HIP_MEMORY_SCOPE_AGENT);
    }
    while (__hip_atomic_load(&S[33], __ATOMIC_RELAXED, __HIP_MEMORY_SCOPE_AGENT) != ph)
      __builtin_amdgcn_s_sleep(1);
    if (t % xtotal == 0u) {                   // first block of this XCD = leader
      asm volatile("buffer_inv sc1\n\ts_waitcnt vmcnt(0)" ::: "memory");
      __hip_atomic_store(&S[16 + x], ph, __ATOMIC_RELAXED, __HIP_MEMORY_SCOPE_AGENT);
    } else {
      while (__hip_atomic_load(&S[16 + x], __ATOMIC_RELAXED, __HIP_MEMORY_SCOPE_AGENT) != ph)
        __builtin_amdgcn_s_sleep(1);
      asm volatile("buffer_inv sc0\n\ts_waitcnt vmcnt(0)" ::: "memory");  // L1 only
    }
  }
  __syncthreads();
}

__global__ void __launch_bounds__(NTHR, 1) lstm_k(Params p) {
  extern __shared__ char smem[];
  f16*   W1s = (f16*)(smem);
  f16*   W2s = (f16*)(smem + OFF_W2);
  float* SgA = (float*)(smem + OFF_SGA);
  float* SgB = (float*)(smem + OFF_SGB);
  float* c1  = (float*)(smem + OFF_C1);
  float* c2  = (float*)(smem + OFF_C2);
  float* bs1 = (float*)(smem + OFF_B1);
  float* bs2 = (float*)(smem + OFF_B2);

  const int tid = threadIdx.x, bid = blockIdx.x;
  const int hb  = bid * 4;
  const int fut = p.fut[0];
  const unsigned xcc = get_xcc();
  unsigned* S = p.S;

  if (bid == 0) {
    if (tid < 16) {
      __hip_atomic_store(&S[tid], 0u, __ATOMIC_RELAXED, __HIP_MEMORY_SCOPE_AGENT);
      __hip_atomic_store(&S[34 + tid], 0u, __ATOMIC_RELAXED, __HIP_MEMORY_SCOPE_AGENT);
    }
    if (tid == 0)
      __hip_atomic_store(&S[32], 0u, __ATOMIC_RELAXED, __HIP_MEMORY_SCOPE_AGENT);
  }

  // ---------------- preamble: weights -> LDS (lane-ordered f16 fragments) --
  // W1s[c*512 + lane*8 + j] = W1[n=col][k=c*32+quad*8+j]; k<1024: Whh1, else Wih1
  for (int idx = tid; idx < 34 * 512; idx += NTHR) {
    int c = idx >> 9, r = idx & 511;
    int q = r >> 7, colw = (r >> 3) & 15, j = r & 7;
    int k = c * 32 + q * 8 + j;
    int row = (colw >> 2) * H_ + hb + (colw & 3);
    float v = (k < H_) ? p.Whh1[row * H_ + k] : p.Wih1[row * DIN + (k - H_)];
    W1s[idx] = (f16)v;
  }
  // W2s: chunks 0..31 vs h1 (Wih2), 32..63 vs h2 (Whh2)
  for (int idx = tid; idx < 64 * 512; idx += NTHR) {
    int c = idx >> 9, r = idx & 511;
    int q = r >> 7, colw = (r >> 3) & 15, j = r & 7;
    int k = c * 32 + q * 8 + j;
    int row = (colw >> 2) * H_ + hb + (colw & 3);
    float v = (k < H_) ? p.Wih2[row * H_ + k] : p.Whh2[row * H_ + (k - H_)];
    W2s[idx] = (f16)v;
  }
  if (tid < 16) {
    int row = (tid >> 2) * H_ + hb + (tid & 3);
    bs1[tid] = p.bih1[row] + p.bhh1[row];
    bs2[tid] = p.bih2[row] + p.bhh2[row];
  }
  for (int i = tid; i < 512; i += NTHR) { c1[i] = 0.f; c2[i] = 0.f; }
  for (int i = bid * NTHR + tid; i < B_ * T_ * DIN; i += NBLK * NTHR)
    p.x16[i] = (f16)p.x[i];
  for (int i = bid * NTHR + tid; i < B_ * H_; i += NBLK * NTHR) {
    p.h1a[i] = (f16)0.f; p.h1b[i] = (f16)0.f;
    p.h2a[i] = (f16)0.f; p.h2b[i] = (f16)0.f;
  }

  unsigned ph = 1;
  grid_sync(p.arrive, p.rel, ph);
  if (tid == 0)
    __hip_atomic_fetch_add(&S[34 + xcc], 1u, __ATOMIC_RELAXED, __HIP_MEMORY_SCOPE_AGENT);
  ++ph;
  grid_sync(p.arrive, p.rel, ph);

  unsigned xtotal = __hip_atomic_load(&S[34 + xcc], __ATOMIC_RELAXED, __HIP_MEMORY_SCOPE_AGENT);
  unsigned nxcd = 0;
  for (int i = 0; i < 16; ++i)
    nxcd += (__hip_atomic_load(&S[34 + i], __ATOMIC_RELAXED, __HIP_MEMORY_SCOPE_AGENT) != 0u);

  auto gsync = [&]() { ++ph; fast_sync(S, xcc, xtotal, nxcd, ph); };

  // ---------- wave geometry: 8 waves = 4 m-tile-pairs x 2 K-halves ---------
  const int lane = tid & 63, wv = tid >> 6;
  const int col = lane & 15, quad = lane >> 4;
  const int mg = wv & 3;               // m-pair: m-tiles {2mg, 2mg+1}
  const int kh = wv >> 2;              // K-half
  const int m0 = mg * 32 + col;        // A row for first m-tile
  const int ko = quad * 8;
  const float b1v = bs1[col], b2v = bs2[col];
  const f16* W1f = W1s + lane * 8;     // conflict-free: 16B/lane sequential
  const f16* W2f = W2s + lane * 8;
  float* Sgw = kh ? SgB : SgA;

  f16 *h1c = p.h1a, *h1n = p.h1b, *h2c = p.h2a, *h2n = p.h2b;

  // fused phase: gates1(t+1) [l1] and gates2(t) [l2], both keyed on h1c
  auto phase = [&](bool l1, bool l2, const f16* xp, int xstr) {
    float4v z = {0.f, 0.f, 0.f, 0.f};
    float4v a10 = z, a11 = z, a20 = z, a21 = z;
    if (kh == 0) {
      a10 = {b1v, b1v, b1v, b1v}; a11 = a10;
      a20 = {b2v, b2v, b2v, b2v}; a21 = a20;
    }
    const int cs = kh * 16, ce = cs + 16;
    const f16* A0 = h1c + m0 * H_ + ko;
    const f16* A1 = A0 + 16 * H_;
    if (l1 && l2) {
      #pragma unroll 8
      for (int c = cs; c < ce; ++c) {
        half8 a0 = *(const half8*)(A0 + c * 32);
        half8 a1 = *(const half8*)(A1 + c * 32);
        half8 w1 = *(const half8*)(W1f + c * 512);
        half8 w2 = *(const half8*)(W2f + c * 512);
        a10 = __builtin_amdgcn_mfma_f32_16x16x32_f16(a0, w1, a10, 0, 0, 0);
        a11 = __builtin_amdgcn_mfma_f32_16x16x32_f16(a1, w1, a11, 0, 0, 0);
        a20 = __builtin_amdgcn_mfma_f32_16x16x32_f16(a0, w2, a20, 0, 0, 0);
        a21 = __builtin_amdgcn_mfma_f32_16x16x32_f16(a1, w2, a21, 0, 0, 0);
      }
    } else if (l1) {
      #pragma unroll 8
      for (int c = cs; c < ce; ++c) {
        half8 a0 = *(const half8*)(A0 + c * 32);
        half8 a1 = *(const half8*)(A1 + c * 32);
        half8 w1 = *(const half8*)(W1f + c * 512);
        a10 = __builtin_amdgcn_mfma_f32_16x16x32_f16(a0, w1, a10, 0, 0, 0);
        a11 = __builtin_amdgcn_mfma_f32_16x16x32_f16(a1, w1, a11, 0, 0, 0);
      }
    } else {
      #pragma unroll 8
      for (int c = cs; c < ce; ++c) {
        half8 a0 = *(const half8*)(A0 + c * 32);
        half8 a1 = *(const half8*)(A1 + c * 32);
        half8 w2 = *(const half8*)(W2f + c * 512);
        a20 = __builtin_amdgcn_mfma_f32_16x16x32_f16(a0, w2, a20, 0, 0, 0);
        a21 = __builtin_amdgcn_mfma_f32_16x16x32_f16(a1, w2, a21, 0, 0, 0);
      }
    }
    if (l2) {  // h2 half of K for gates2: W2 chunks 32+c
      const f16* C0 = h2c + m0 * H_ + ko;
      const f16* C1 = C0 + 16 * H_;
      #pragma unroll 8
      for (int c = cs; c < ce; ++c) {
        half8 a0 = *(const half8*)(C0 + c * 32);
        half8 a1 = *(const half8*)(C1 + c * 32);
        half8 w2 = *(const half8*)(W2f + (32 + c) * 512);
        a20 = __builtin_amdgcn_mfma_f32_16x16x32_f16(a0, w2, a20, 0, 0, 0);
        a21 = __builtin_amdgcn_mfma_f32_16x16x32_f16(a1, w2, a21, 0, 0, 0);
      }
    }
    if (l1 && kh == 1) {  // x part: W1 chunks 32..33 (only K-half-1 waves)
      #pragma unroll
      for (int kx = 0; kx < 2; ++kx) {
        half8 a0 = *(const half8*)(xp + m0 * xstr + kx * 32 + ko);
        half8 a1 = *(const half8*)(xp + (m0 + 16) * xstr + kx * 32 + ko);
        half8 w1 = *(const half8*)(W1f + (32 + kx) * 512);
        a10 = __builtin_amdgcn_mfma_f32_16x16x32_f16(a0, w1, a10, 0, 0, 0);
        a11 = __builtin_amdgcn_mfma_f32_16x16x32_f16(a1, w1, a11, 0, 0, 0);
      }
    }
    // ---- epilogues: partial transpose via LDS, combine, LSTM pointwise ----
    if (l1) {
      __syncthreads();
      #pragma unroll
      for (int r = 0; r < 4; ++r) {
        Sgw[((mg * 2) * 16 + quad * 4 + r) * 17 + col]     = a10[r];
        Sgw[((mg * 2 + 1) * 16 + quad * 4 + r) * 17 + col] = a11[r];
      }
      __syncthreads();
      {
        int mm = tid >> 2, cc = tid & 3;
        float gi = SgA[mm * 17 + cc]      + SgB[mm * 17 + cc];
        float gf = SgA[mm * 17 + 4 + cc]  + SgB[mm * 17 + 4 + cc];
        float gg = SgA[mm * 17 + 8 + cc]  + SgB[mm * 17 + 8 + cc];
        float go = SgA[mm * 17 + 12 + cc] + SgB[mm * 17 + 12 + cc];
        float cn = sigm(gf) * c1[tid] + sigm(gi) * tanh_(gg);
        c1[tid] = cn;
        h1n[mm * H_ + hb + cc] = (f16)(sigm(go) * tanh_(cn));
      }
    }
    if (l2) {
      __syncthreads();
      #pragma unroll
      for (int r = 0; r < 4; ++r) {
        Sgw[((mg * 2) * 16 + quad * 4 + r) * 17 + col]     = a20[r];
        Sgw[((mg * 2 + 1) * 16 + quad * 4 + r) * 17 + col] = a21[r];
      }
      __syncthreads();
      {
        int mm = tid >> 2, cc = tid & 3;
        float gi = SgA[mm * 17 + cc]      + SgB[mm * 17 + cc];
        float gf = SgA[mm * 17 + 4 + cc]  + SgB[mm * 17 + 4 + cc];
        float gg = SgA[mm * 17 + 8 + cc]  + SgB[mm * 17 + 8 + cc];
        float go = SgA[mm * 17 + 12 + cc] + SgB[mm * 17 + 12 + cc];
        float cn = sigm(gf) * c2[tid] + sigm(gi) * tanh_(gg);
        c2[tid] = cn;
        h2n[mm * H_ + hb + cc] = (f16)(sigm(go) * tanh_(cn));
      }
    }
  };

  // small projection: out[m][j] = h2 . W[j] + b[j]  (fp32 weights)
  auto out_phase = [&](const float* W, const float* bv, bool wout) {
    int j = bid & 63, mgp = bid >> 6;
    int rid = tid >> 4, ks = tid & 15;
    int mrow = mgp * 32 + rid;
    const f16* hr = h2c + mrow * H_ + ks * 64;
    const float* wr = W + j * H_ + ks * 64;
    float s = 0.f;
    #pragma unroll 8
    for (int k = 0; k < 64; ++k) s += (float)hr[k] * wr[k];
    s += __shfl_down(s, 8, 16);
    s += __shfl_down(s, 4, 16);
    s += __shfl_down(s, 2, 16);
    s += __shfl_down(s, 1, 16);
    if (ks == 0) {
      float v = s + bv[j];
      p.ob[mrow * 64 + j] = (f16)v;
      if (wout) p.out[mrow * 64 + j] = v;
    }
  };

  // ---------------- time loop: 129 fused phases ----------------------------
  for (int t = -1; t < T_; ++t) {
    bool l1 = (t + 1 < T_), l2 = (t >= 0);
    phase(l1, l2, p.x16 + (t + 1) * DIN, T_ * DIN);
    gsync();
    if (l1) { f16* tm = h1c; h1c = h1n; h1n = tm; }
    if (l2) { f16* tm = h2c; h2c = h2n; h2n = tm; }
  }
  out_phase(p.Wlin, p.blin, fut == 0);
  gsync();
  for (int f = 0; f < fut; ++f) {
    phase(true, false, p.ob, 64);
    gsync();
    { f16* tm = h1c; h1c = h1n; h1n = tm; }
    phase(false, true, p.ob, 64);
    gsync();
    { f16* tm = h2c; h2c = h2n; h2n = tm; }
    out_phase(p.Whio, p.bhio, f == fut - 1);
    gsync();
  }
}

extern "C" void kernel_launch(void* const* d_in, const int* in_sizes, int n_in,
                              void* d_out, int out_size, void* d_ws, size_t ws_size,
                              hipStream_t stream) {
  char* w = (char*)d_ws;
  auto carve = [&](size_t n) { char* r = w; w += (n + 255) & ~(size_t)255; return r; };

  Params p;
  p.x    = (const float*)d_in[0];
  p.Wih1 = (const float*)d_in[1];
  p.Whh1 = (const float*)d_in[2];
  p.bih1 = (const float*)d_in[3];
  p.bhh1 = (const float*)d_in[4];
  p.Wih2 = (const float*)d_in[5];
  p.Whh2 = (const float*)d_in[6];
  p.bih2 = (const float*)d_in[7];
  p.bhh2 = (const float*)d_in[8];
  p.Wlin = (const float*)d_in[9];
  p.blin = (const float*)d_in[10];
  p.Whio = (const float*)d_in[11];
  p.bhio = (const float*)d_in[12];
  p.fut  = (const int*)d_in[13];
  p.out  = (float*)d_out;

  p.x16 = (f16*)carve((size_t)B_ * T_ * DIN * 2);
  p.h1a = (f16*)carve((size_t)B_ * H_ * 2);
  p.h1b = (f16*)carve((size_t)B_ * H_ * 2);
  p.h2a = (f16*)carve((size_t)B_ * H_ * 2);
  p.h2b = (f16*)carve((size_t)B_ * H_ * 2);
  p.ob  = (f16*)carve((size_t)B_ * 64 * 2);
  p.arrive = (unsigned*)carve(NBLK * sizeof(unsigned));
  p.rel    = (unsigned*)carve(256);
  p.S      = (unsigned*)carve(64 * sizeof(unsigned));

  (void)hipFuncSetAttribute((const void*)lstm_k,
                            hipFuncAttributeMaxDynamicSharedMemorySize, SMEM_BYTES);
  void* args[] = { &p };
  (void)hipLaunchCooperativeKernel((void*)lstm_k, dim3(NBLK), dim3(NTHR),
                                   args, SMEM_BYTES, stream);
}

// Round 4
// 3056.255 us; speedup vs baseline: 1.0234x; 1.0234x over previous
//
#include <hip/hip_runtime.h>

#define B_   128
#define T_   128
#define DIN  64
#define H_   1024
#define NBLK 256
#define NTHR 512

typedef _Float16 f16;
typedef _Float16 half8 __attribute__((ext_vector_type(8)));
typedef float float4v __attribute__((ext_vector_type(4)));

// LDS layout (dynamic shared), W in lane-ordered MFMA fragment layout:
//  W1s: f16[34][512]  chunk-major, lane*8 within chunk (16B/lane)   34816 B
//  W2s: f16[64][512]                                                65536 B
//  SG1: float[2][128][17] layer-1 gate partials (per K-half)        17408 B
//  SG2: float[2][128][17] layer-2 gate partials                    17408 B
//  c1 : float[512], c2 : float[512]                                  4096 B
//  bs1: float[16], bs2: float[16]                                     128 B
#define OFF_W2  34816
#define OFF_SG1 100352
#define OFF_SG2 117760
#define OFF_C1  135168
#define OFF_C2  137216
#define OFF_B1  139264
#define OFF_B2  139328
#define SMEM_BYTES 139392

struct Params {
  const float *x, *Wih1, *Whh1, *bih1, *bhh1, *Wih2, *Whh2, *bih2, *bhh2,
              *Wlin, *blin, *Whio, *bhio;
  const int* fut;
  float* out;
  f16 *x16, *h1a, *h1b, *h2a, *h2b, *ob;
  unsigned *arrive, *rel;
  unsigned *S;   // [0..15] xtick, [16..31] xflag, [32] central, [33] release, [34..49] xtot
};

__device__ __forceinline__ float sigm(float v) { return 1.f / (1.f + __expf(-v)); }
__device__ __forceinline__ float tanh_(float v) { return 2.f / (1.f + __expf(-2.f * v)) - 1.f; }

__device__ __forceinline__ unsigned get_xcc() {
  unsigned x;
  asm volatile("s_getreg_b32 %0, hwreg(HW_REG_XCC_ID)" : "=s"(x));
  return x & 15u;
}

// ---- slow barrier (preamble only): full release/acquire, known-correct ----
__device__ __forceinline__ void grid_sync(unsigned* arrive, unsigned* rel, unsigned ph) {
  __syncthreads();
  const int tid = threadIdx.x, bid = blockIdx.x;
  if (bid == 0) {
    if (tid > 0 && tid < NBLK) {
      while (__hip_atomic_load(&arrive[tid], __ATOMIC_RELAXED, __HIP_MEMORY_SCOPE_AGENT) != ph)
        __builtin_amdgcn_s_sleep(1);
    }
    __syncthreads();
    if (tid == 0)
      __hip_atomic_store(rel, ph, __ATOMIC_RELEASE, __HIP_MEMORY_SCOPE_AGENT);
  } else {
    if (tid == 0) {
      __hip_atomic_store(&arrive[bid], ph, __ATOMIC_RELEASE, __HIP_MEMORY_SCOPE_AGENT);
      while (__hip_atomic_load(rel, __ATOMIC_RELAXED, __HIP_MEMORY_SCOPE_AGENT) != ph)
        __builtin_amdgcn_s_sleep(1);
    }
  }
  __syncthreads();
  __builtin_amdgcn_fence(__ATOMIC_ACQUIRE, "agent");
}

// ---- fast barrier v2: NO wbl2 (h-exchange is write-through atomics).
// arrive -> central -> release -> poll; leader invs L1+L2, others inv L1
// early (concurrent with leader) then wait xflag. Spin-until-equal phases.
__device__ __forceinline__ void fast_sync(unsigned* S, unsigned x, unsigned xtotal,
                                          unsigned nxcd, unsigned ph) {
  __syncthreads();   // includes s_waitcnt vmcnt(0): h atomic stores at coherence point
  if (threadIdx.x == 0) {
    unsigned t = __hip_atomic_fetch_add(&S[x], 1u, __ATOMIC_RELAXED, __HIP_MEMORY_SCOPE_AGENT);
    if ((t + 1u) % xtotal == 0u) {            // last block of this XCD
      unsigned c = __hip_atomic_fetch_add(&S[32], 1u, __ATOMIC_RELAXED, __HIP_MEMORY_SCOPE_AGENT);
      if ((c + 1u) % nxcd == 0u)              // last XCD globally -> release
        __hip_atomic_store(&S[33], ph, __ATOMIC_RELAXED, __HIP_MEMORY_SCOPE_AGENT);
    }
    bool leader = (t % xtotal == 0u);
    while (__hip_atomic_load(&S[33], __ATOMIC_RELAXED, __HIP_MEMORY_SCOPE_AGENT) != ph)
      __builtin_amdgcn_s_sleep(1);
    if (leader) {
      asm volatile("buffer_inv sc0 sc1\n\ts_waitcnt vmcnt(0)" ::: "memory");
      __hip_atomic_store(&S[16 + x], ph, __ATOMIC_RELAXED, __HIP_MEMORY_SCOPE_AGENT);
    } else {
      asm volatile("buffer_inv sc0\n\ts_waitcnt vmcnt(0)" ::: "memory");  // local L1, overlaps leader
      while (__hip_atomic_load(&S[16 + x], __ATOMIC_RELAXED, __HIP_MEMORY_SCOPE_AGENT) != ph)
        __builtin_amdgcn_s_sleep(1);
    }
  }
  __syncthreads();
}

__global__ void __launch_bounds__(NTHR, 1) lstm_k(Params p) {
  extern __shared__ char smem[];
  f16*   W1s = (f16*)(smem);
  f16*   W2s = (f16*)(smem + OFF_W2);
  float* SG1 = (float*)(smem + OFF_SG1);   // [2][2176]
  float* SG2 = (float*)(smem + OFF_SG2);
  float* c1  = (float*)(smem + OFF_C1);
  float* c2  = (float*)(smem + OFF_C2);
  float* bs1 = (float*)(smem + OFF_B1);
  float* bs2 = (float*)(smem + OFF_B2);

  const int tid = threadIdx.x, bid = blockIdx.x;
  const int hb  = bid * 4;
  const int fut = p.fut[0];
  const unsigned xcc = get_xcc();
  unsigned* S = p.S;

  if (bid == 0) {
    if (tid < 16) {
      __hip_atomic_store(&S[tid], 0u, __ATOMIC_RELAXED, __HIP_MEMORY_SCOPE_AGENT);
      __hip_atomic_store(&S[34 + tid], 0u, __ATOMIC_RELAXED, __HIP_MEMORY_SCOPE_AGENT);
    }
    if (tid == 0)
      __hip_atomic_store(&S[32], 0u, __ATOMIC_RELAXED, __HIP_MEMORY_SCOPE_AGENT);
  }

  // ---------------- preamble: weights -> LDS (lane-ordered f16 fragments) --
  for (int idx = tid; idx < 34 * 512; idx += NTHR) {
    int c = idx >> 9, r = idx & 511;
    int q = r >> 7, colw = (r >> 3) & 15, j = r & 7;
    int k = c * 32 + q * 8 + j;
    int row = (colw >> 2) * H_ + hb + (colw & 3);
    float v = (k < H_) ? p.Whh1[row * H_ + k] : p.Wih1[row * DIN + (k - H_)];
    W1s[idx] = (f16)v;
  }
  for (int idx = tid; idx < 64 * 512; idx += NTHR) {
    int c = idx >> 9, r = idx & 511;
    int q = r >> 7, colw = (r >> 3) & 15, j = r & 7;
    int k = c * 32 + q * 8 + j;
    int row = (colw >> 2) * H_ + hb + (colw & 3);
    float v = (k < H_) ? p.Wih2[row * H_ + k] : p.Whh2[row * H_ + (k - H_)];
    W2s[idx] = (f16)v;
  }
  if (tid < 16) {
    int row = (tid >> 2) * H_ + hb + (tid & 3);
    bs1[tid] = p.bih1[row] + p.bhh1[row];
    bs2[tid] = p.bih2[row] + p.bhh2[row];
  }
  for (int i = tid; i < 512; i += NTHR) { c1[i] = 0.f; c2[i] = 0.f; }
  for (int i = bid * NTHR + tid; i < B_ * T_ * DIN; i += NBLK * NTHR)
    p.x16[i] = (f16)p.x[i];
  for (int i = bid * NTHR + tid; i < B_ * H_; i += NBLK * NTHR) {
    p.h1a[i] = (f16)0.f; p.h1b[i] = (f16)0.f;
    p.h2a[i] = (f16)0.f; p.h2b[i] = (f16)0.f;
  }

  unsigned ph = 1;
  grid_sync(p.arrive, p.rel, ph);
  if (tid == 0)
    __hip_atomic_fetch_add(&S[34 + xcc], 1u, __ATOMIC_RELAXED, __HIP_MEMORY_SCOPE_AGENT);
  ++ph;
  grid_sync(p.arrive, p.rel, ph);

  unsigned xtotal = __hip_atomic_load(&S[34 + xcc], __ATOMIC_RELAXED, __HIP_MEMORY_SCOPE_AGENT);
  unsigned nxcd = 0;
  for (int i = 0; i < 16; ++i)
    nxcd += (__hip_atomic_load(&S[34 + i], __ATOMIC_RELAXED, __HIP_MEMORY_SCOPE_AGENT) != 0u);

  auto gsync = [&]() { ++ph; fast_sync(S, xcc, xtotal, nxcd, ph); };

  // ---------- wave geometry: 8 waves = 4 m-tile-pairs x 2 K-halves ---------
  const int lane = tid & 63, wv = tid >> 6;
  const int col = lane & 15, quad = lane >> 4;
  const int mg = wv & 3;               // m-pair: m-tiles {2mg, 2mg+1}
  const int kh = wv >> 2;              // K-half
  const int m0 = mg * 32 + col;
  const int ko = quad * 8;
  const float b1v = bs1[col], b2v = bs2[col];
  const f16* W1f = W1s + lane * 8;
  const f16* W2f = W2s + lane * 8;
  float* Sg1w = SG1 + kh * 2176;
  float* Sg2w = SG2 + kh * 2176;

  f16 *h1c = p.h1a, *h1n = p.h1b, *h2c = p.h2a, *h2n = p.h2b;

  // pointwise + shfl-pack + write-through u64 store of 4 f16
  auto lstm_pw = [&](const float* Sgb, float* cst, f16* hn) {
    int mm = tid >> 2, cc = tid & 3;
    float gi = Sgb[mm * 17 + cc]      + Sgb[2176 + mm * 17 + cc];
    float gf = Sgb[mm * 17 + 4 + cc]  + Sgb[2176 + mm * 17 + 4 + cc];
    float gg = Sgb[mm * 17 + 8 + cc]  + Sgb[2176 + mm * 17 + 8 + cc];
    float go = Sgb[mm * 17 + 12 + cc] + Sgb[2176 + mm * 17 + 12 + cc];
    float cn = sigm(gf) * cst[tid] + sigm(gi) * tanh_(gg);
    cst[tid] = cn;
    f16 hv = (f16)(sigm(go) * tanh_(cn));
    int v = (int)__builtin_bit_cast(unsigned short, hv);
    int base = lane & ~3;
    int v0 = __shfl(v, base, 64),     v1 = __shfl(v, base + 1, 64);
    int v2 = __shfl(v, base + 2, 64), v3 = __shfl(v, base + 3, 64);
    if (cc == 0) {
      unsigned long long pk = (unsigned long long)(unsigned short)v0
        | ((unsigned long long)(unsigned short)v1 << 16)
        | ((unsigned long long)(unsigned short)v2 << 32)
        | ((unsigned long long)(unsigned short)v3 << 48);
      __hip_atomic_store((unsigned long long*)(hn + mm * H_ + hb), pk,
                         __ATOMIC_RELAXED, __HIP_MEMORY_SCOPE_AGENT);
    }
  };

  // fused phase: gates1(t+1) [l1] and gates2(t) [l2], both keyed on h1c
  auto phase = [&](bool l1, bool l2, const f16* xp, int xstr) {
    float4v z = {0.f, 0.f, 0.f, 0.f};
    float4v a10 = z, a11 = z, a20 = z, a21 = z;
    if (kh == 0) {
      a10 = {b1v, b1v, b1v, b1v}; a11 = a10;
      a20 = {b2v, b2v, b2v, b2v}; a21 = a20;
    }
    const int cs = kh * 16, ce = cs + 16;
    const f16* A0 = h1c + m0 * H_ + ko;
    const f16* A1 = A0 + 16 * H_;
    if (l1 && l2) {
      #pragma unroll 8
      for (int c = cs; c < ce; ++c) {
        half8 a0 = *(const half8*)(A0 + c * 32);
        half8 a1 = *(const half8*)(A1 + c * 32);
        half8 w1 = *(const half8*)(W1f + c * 512);
        half8 w2 = *(const half8*)(W2f + c * 512);
        a10 = __builtin_amdgcn_mfma_f32_16x16x32_f16(a0, w1, a10, 0, 0, 0);
        a11 = __builtin_amdgcn_mfma_f32_16x16x32_f16(a1, w1, a11, 0, 0, 0);
        a20 = __builtin_amdgcn_mfma_f32_16x16x32_f16(a0, w2, a20, 0, 0, 0);
        a21 = __builtin_amdgcn_mfma_f32_16x16x32_f16(a1, w2, a21, 0, 0, 0);
      }
    } else if (l1) {
      #pragma unroll 8
      for (int c = cs; c < ce; ++c) {
        half8 a0 = *(const half8*)(A0 + c * 32);
        half8 a1 = *(const half8*)(A1 + c * 32);
        half8 w1 = *(const half8*)(W1f + c * 512);
        a10 = __builtin_amdgcn_mfma_f32_16x16x32_f16(a0, w1, a10, 0, 0, 0);
        a11 = __builtin_amdgcn_mfma_f32_16x16x32_f16(a1, w1, a11, 0, 0, 0);
      }
    } else {
      #pragma unroll 8
      for (int c = cs; c < ce; ++c) {
        half8 a0 = *(const half8*)(A0 + c * 32);
        half8 a1 = *(const half8*)(A1 + c * 32);
        half8 w2 = *(const half8*)(W2f + c * 512);
        a20 = __builtin_amdgcn_mfma_f32_16x16x32_f16(a0, w2, a20, 0, 0, 0);
        a21 = __builtin_amdgcn_mfma_f32_16x16x32_f16(a1, w2, a21, 0, 0, 0);
      }
    }
    if (l2) {  // h2 half of K for gates2: W2 chunks 32+c
      const f16* C0 = h2c + m0 * H_ + ko;
      const f16* C1 = C0 + 16 * H_;
      #pragma unroll 8
      for (int c = cs; c < ce; ++c) {
        half8 a0 = *(const half8*)(C0 + c * 32);
        half8 a1 = *(const half8*)(C1 + c * 32);
        half8 w2 = *(const half8*)(W2f + (32 + c) * 512);
        a20 = __builtin_amdgcn_mfma_f32_16x16x32_f16(a0, w2, a20, 0, 0, 0);
        a21 = __builtin_amdgcn_mfma_f32_16x16x32_f16(a1, w2, a21, 0, 0, 0);
      }
    }
    if (l1 && kh == 1) {  // x part: W1 chunks 32..33 (only K-half-1 waves)
      #pragma unroll
      for (int kx = 0; kx < 2; ++kx) {
        half8 a0 = *(const half8*)(xp + m0 * xstr + kx * 32 + ko);
        half8 a1 = *(const half8*)(xp + (m0 + 16) * xstr + kx * 32 + ko);
        half8 w1 = *(const half8*)(W1f + (32 + kx) * 512);
        a10 = __builtin_amdgcn_mfma_f32_16x16x32_f16(a0, w1, a10, 0, 0, 0);
        a11 = __builtin_amdgcn_mfma_f32_16x16x32_f16(a1, w1, a11, 0, 0, 0);
      }
    }
    // ---- merged epilogue: one sync pair for both layers ----
    __syncthreads();   // previous phase's Sg reads are done; safe to overwrite
    if (l1) {
      #pragma unroll
      for (int r = 0; r < 4; ++r) {
        Sg1w[((mg * 2) * 16 + quad * 4 + r) * 17 + col]     = a10[r];
        Sg1w[((mg * 2 + 1) * 16 + quad * 4 + r) * 17 + col] = a11[r];
      }
    }
    if (l2) {
      #pragma unroll
      for (int r = 0; r < 4; ++r) {
        Sg2w[((mg * 2) * 16 + quad * 4 + r) * 17 + col]     = a20[r];
        Sg2w[((mg * 2 + 1) * 16 + quad * 4 + r) * 17 + col] = a21[r];
      }
    }
    __syncthreads();
    if (l1) lstm_pw(SG1, c1, h1n);
    if (l2) lstm_pw(SG2, c2, h2n);
  };

  // small projection: out[m][j] = h2 . W[j] + b[j]  (fp32 weights)
  auto out_phase = [&](const float* W, const float* bv, bool wout) {
    int j = bid & 63, mgp = bid >> 6;
    int rid = tid >> 4, ks = tid & 15;
    int mrow = mgp * 32 + rid;
    const f16* hr = h2c + mrow * H_ + ks * 64;
    const float* wr = W + j * H_ + ks * 64;
    float s = 0.f;
    #pragma unroll 8
    for (int k = 0; k < 64; ++k) s += (float)hr[k] * wr[k];
    s += __shfl_down(s, 8, 16);
    s += __shfl_down(s, 4, 16);
    s += __shfl_down(s, 2, 16);
    s += __shfl_down(s, 1, 16);
    if (ks == 0) {
      float v = s + bv[j];
      f16 hv = (f16)v;
      __hip_atomic_store((unsigned short*)&p.ob[mrow * 64 + j],
                         __builtin_bit_cast(unsigned short, hv),
                         __ATOMIC_RELAXED, __HIP_MEMORY_SCOPE_AGENT);
      if (wout) p.out[mrow * 64 + j] = v;
    }
  };

  // ---------------- time loop: 129 fused phases ----------------------------
  for (int t = -1; t < T_; ++t) {
    bool l1 = (t + 1 < T_), l2 = (t >= 0);
    phase(l1, l2, p.x16 + (t + 1) * DIN, T_ * DIN);
    gsync();
    if (l1) { f16* tm = h1c; h1c = h1n; h1n = tm; }
    if (l2) { f16* tm = h2c; h2c = h2n; h2n = tm; }
  }
  out_phase(p.Wlin, p.blin, fut == 0);
  gsync();
  for (int f = 0; f < fut; ++f) {
    phase(true, false, p.ob, 64);
    gsync();
    { f16* tm = h1c; h1c = h1n; h1n = tm; }
    phase(false, true, p.ob, 64);
    gsync();
    { f16* tm = h2c; h2c = h2n; h2n = tm; }
    out_phase(p.Whio, p.bhio, f == fut - 1);
    gsync();
  }
}

extern "C" void kernel_launch(void* const* d_in, const int* in_sizes, int n_in,
                              void* d_out, int out_size, void* d_ws, size_t ws_size,
                              hipStream_t stream) {
  char* w = (char*)d_ws;
  auto carve = [&](size_t n) { char* r = w; w += (n + 255) & ~(size_t)255; return r; };

  Params p;
  p.x    = (const float*)d_in[0];
  p.Wih1 = (const float*)d_in[1];
  p.Whh1 = (const float*)d_in[2];
  p.bih1 = (const float*)d_in[3];
  p.bhh1 = (const float*)d_in[4];
  p.Wih2 = (const float*)d_in[5];
  p.Whh2 = (const float*)d_in[6];
  p.bih2 = (const float*)d_in[7];
  p.bhh2 = (const float*)d_in[8];
  p.Wlin = (const float*)d_in[9];
  p.blin = (const float*)d_in[10];
  p.Whio = (const float*)d_in[11];
  p.bhio = (const float*)d_in[12];
  p.fut  = (const int*)d_in[13];
  p.out  = (float*)d_out;

  p.x16 = (f16*)carve((size_t)B_ * T_ * DIN * 2);
  p.h1a = (f16*)carve((size_t)B_ * H_ * 2);
  p.h1b = (f16*)carve((size_t)B_ * H_ * 2);
  p.h2a = (f16*)carve((size_t)B_ * H_ * 2);
  p.h2b = (f16*)carve((size_t)B_ * H_ * 2);
  p.ob  = (f16*)carve((size_t)B_ * 64 * 2);
  p.arrive = (unsigned*)carve(NBLK * sizeof(unsigned));
  p.rel    = (unsigned*)carve(256);
  p.S      = (unsigned*)carve(64 * sizeof(unsigned));

  (void)hipFuncSetAttribute((const void*)lstm_k,
                            hipFuncAttributeMaxDynamicSharedMemorySize, SMEM_BYTES);
  void* args[] = { &p };
  (void)hipLaunchCooperativeKernel((void*)lstm_k, dim3(NBLK), dim3(NTHR),
                                   args, SMEM_BYTES, stream);
}

// Round 5
// 2970.455 us; speedup vs baseline: 1.0530x; 1.0289x over previous
//
#include <hip/hip_runtime.h>

#define B_   128
#define T_   128
#define DIN  64
#define H_   1024
#define NBLK 256
#define NTHR 512
#define NSLOT 6
#define DEPTH 5

typedef _Float16 f16;
typedef _Float16 half8 __attribute__((ext_vector_type(8)));
typedef float float4v __attribute__((ext_vector_type(4)));

// LDS layout:
//  W1s : f16[34][512]  lane-ordered fragments                34816 B
//  W2s : f16[64][512]                                        65536 B
//  RING: f16[8 waves][6 slots][512]  A-stream DMA ring       49152 B
//  Sg  : float[128][17]                                       8704 B
//  c1,c2: float[512] each                                     4096 B
//  bs1,bs2: float[16] each                                     128 B
#define OFF_W2   34816
#define OFF_RING 100352
#define OFF_SG   149504
#define OFF_C1   158208
#define OFF_C2   160256
#define OFF_B1   162304
#define OFF_B2   162368
#define SMEM_BYTES 162432

struct Params {
  const float *x, *Wih1, *Whh1, *bih1, *bhh1, *Wih2, *Whh2, *bih2, *bhh2,
              *Wlin, *blin, *Whio, *bhio;
  const int* fut;
  float* out;
  f16 *x16, *h1a, *h1b, *h2a, *h2b, *ob;
  unsigned *arrive, *rel;
  unsigned *S;   // [0..15] xtick, [16..31] xflag, [32] central, [33] release, [34..49] xtot
};

__device__ __forceinline__ float sigm(float v) { return 1.f / (1.f + __expf(-v)); }
__device__ __forceinline__ float tanh_(float v) { return 2.f / (1.f + __expf(-2.f * v)) - 1.f; }

__device__ __forceinline__ unsigned get_xcc() {
  unsigned x;
  asm volatile("s_getreg_b32 %0, hwreg(HW_REG_XCC_ID)" : "=s"(x));
  return x & 15u;
}

// DMA one 32-k window (16 rows x 32 k, fragment-ordered) into an LDS slot.
__device__ __forceinline__ void stage_dma(const f16* src_lane, f16* lds_base) {
  __builtin_amdgcn_global_load_lds(
      (const __attribute__((address_space(1))) void*)src_lane,
      (__attribute__((address_space(3))) void*)lds_base, 16, 0, 0);
}

#define WAIT_VM(n)                                                        \
  do {                                                                    \
    switch (n) {                                                          \
      case 4: asm volatile("s_waitcnt vmcnt(4)" ::: "memory"); break;     \
      case 3: asm volatile("s_waitcnt vmcnt(3)" ::: "memory"); break;     \
      case 2: asm volatile("s_waitcnt vmcnt(2)" ::: "memory"); break;     \
      case 1: asm volatile("s_waitcnt vmcnt(1)" ::: "memory"); break;     \
      default: asm volatile("s_waitcnt vmcnt(0)" ::: "memory"); break;    \
    }                                                                     \
  } while (0)

// ---- slow barrier (preamble only) -----------------------------------------
__device__ __forceinline__ void grid_sync(unsigned* arrive, unsigned* rel, unsigned ph) {
  __syncthreads();
  const int tid = threadIdx.x, bid = blockIdx.x;
  if (bid == 0) {
    if (tid > 0 && tid < NBLK) {
      while (__hip_atomic_load(&arrive[tid], __ATOMIC_RELAXED, __HIP_MEMORY_SCOPE_AGENT) != ph)
        __builtin_amdgcn_s_sleep(1);
    }
    __syncthreads();
    if (tid == 0)
      __hip_atomic_store(rel, ph, __ATOMIC_RELEASE, __HIP_MEMORY_SCOPE_AGENT);
  } else {
    if (tid == 0) {
      __hip_atomic_store(&arrive[bid], ph, __ATOMIC_RELEASE, __HIP_MEMORY_SCOPE_AGENT);
      while (__hip_atomic_load(rel, __ATOMIC_RELAXED, __HIP_MEMORY_SCOPE_AGENT) != ph)
        __builtin_amdgcn_s_sleep(1);
    }
  }
  __syncthreads();
  __builtin_amdgcn_fence(__ATOMIC_ACQUIRE, "agent");
}

// ---- fast barrier: no wbl2 (h-exchange is write-through atomics) ----------
__device__ __forceinline__ void fast_sync(unsigned* S, unsigned x, unsigned xtotal,
                                          unsigned nxcd, unsigned ph) {
  __syncthreads();
  if (threadIdx.x == 0) {
    unsigned t = __hip_atomic_fetch_add(&S[x], 1u, __ATOMIC_RELAXED, __HIP_MEMORY_SCOPE_AGENT);
    if ((t + 1u) % xtotal == 0u) {
      unsigned c = __hip_atomic_fetch_add(&S[32], 1u, __ATOMIC_RELAXED, __HIP_MEMORY_SCOPE_AGENT);
      if ((c + 1u) % nxcd == 0u)
        __hip_atomic_store(&S[33], ph, __ATOMIC_RELAXED, __HIP_MEMORY_SCOPE_AGENT);
    }
    bool leader = (t % xtotal == 0u);
    while (__hip_atomic_load(&S[33], __ATOMIC_RELAXED, __HIP_MEMORY_SCOPE_AGENT) != ph)
      __builtin_amdgcn_s_sleep(1);
    if (leader) {
      asm volatile("buffer_inv sc0 sc1\n\ts_waitcnt vmcnt(0)" ::: "memory");
      __hip_atomic_store(&S[16 + x], ph, __ATOMIC_RELAXED, __HIP_MEMORY_SCOPE_AGENT);
    } else {
      asm volatile("buffer_inv sc0\n\ts_waitcnt vmcnt(0)" ::: "memory");
      while (__hip_atomic_load(&S[16 + x], __ATOMIC_RELAXED, __HIP_MEMORY_SCOPE_AGENT) != ph)
        __builtin_amdgcn_s_sleep(1);
    }
  }
  __syncthreads();
}

__global__ void __launch_bounds__(NTHR, 1) lstm_k(Params p) {
  extern __shared__ char smem[];
  f16*   W1s  = (f16*)(smem);
  f16*   W2s  = (f16*)(smem + OFF_W2);
  f16*   RING = (f16*)(smem + OFF_RING);
  float* Sg   = (float*)(smem + OFF_SG);
  float* c1   = (float*)(smem + OFF_C1);
  float* c2   = (float*)(smem + OFF_C2);
  float* bs1  = (float*)(smem + OFF_B1);
  float* bs2  = (float*)(smem + OFF_B2);

  const int tid = threadIdx.x, bid = blockIdx.x;
  const int hb  = bid * 4;
  const int fut = p.fut[0];
  const unsigned xcc = get_xcc();
  unsigned* S = p.S;

  if (bid == 0) {
    if (tid < 16) {
      __hip_atomic_store(&S[tid], 0u, __ATOMIC_RELAXED, __HIP_MEMORY_SCOPE_AGENT);
      __hip_atomic_store(&S[34 + tid], 0u, __ATOMIC_RELAXED, __HIP_MEMORY_SCOPE_AGENT);
    }
    if (tid == 0)
      __hip_atomic_store(&S[32], 0u, __ATOMIC_RELAXED, __HIP_MEMORY_SCOPE_AGENT);
  }

  // ---------------- preamble ------------------------------------------------
  for (int idx = tid; idx < 34 * 512; idx += NTHR) {
    int c = idx >> 9, r = idx & 511;
    int q = r >> 7, colw = (r >> 3) & 15, j = r & 7;
    int k = c * 32 + q * 8 + j;
    int row = (colw >> 2) * H_ + hb + (colw & 3);
    float v = (k < H_) ? p.Whh1[row * H_ + k] : p.Wih1[row * DIN + (k - H_)];
    W1s[idx] = (f16)v;
  }
  for (int idx = tid; idx < 64 * 512; idx += NTHR) {
    int c = idx >> 9, r = idx & 511;
    int q = r >> 7, colw = (r >> 3) & 15, j = r & 7;
    int k = c * 32 + q * 8 + j;
    int row = (colw >> 2) * H_ + hb + (colw & 3);
    float v = (k < H_) ? p.Wih2[row * H_ + k] : p.Whh2[row * H_ + (k - H_)];
    W2s[idx] = (f16)v;
  }
  if (tid < 16) {
    int row = (tid >> 2) * H_ + hb + (tid & 3);
    bs1[tid] = p.bih1[row] + p.bhh1[row];
    bs2[tid] = p.bih2[row] + p.bhh2[row];
  }
  for (int i = tid; i < 512; i += NTHR) { c1[i] = 0.f; c2[i] = 0.f; }
  for (int i = bid * NTHR + tid; i < B_ * T_ * DIN; i += NBLK * NTHR)
    p.x16[i] = (f16)p.x[i];
  for (int i = bid * NTHR + tid; i < B_ * H_; i += NBLK * NTHR) {
    p.h1a[i] = (f16)0.f; p.h1b[i] = (f16)0.f;
    p.h2a[i] = (f16)0.f; p.h2b[i] = (f16)0.f;
  }

  unsigned ph = 1;
  grid_sync(p.arrive, p.rel, ph);
  if (tid == 0)
    __hip_atomic_fetch_add(&S[34 + xcc], 1u, __ATOMIC_RELAXED, __HIP_MEMORY_SCOPE_AGENT);
  ++ph;
  grid_sync(p.arrive, p.rel, ph);

  unsigned xtotal = __hip_atomic_load(&S[34 + xcc], __ATOMIC_RELAXED, __HIP_MEMORY_SCOPE_AGENT);
  unsigned nxcd = 0;
  for (int i = 0; i < 16; ++i)
    nxcd += (__hip_atomic_load(&S[34 + i], __ATOMIC_RELAXED, __HIP_MEMORY_SCOPE_AGENT) != 0u);

  auto gsync = [&]() { ++ph; fast_sync(S, xcc, xtotal, nxcd, ph); };

  // ---------- wave geometry: 8 waves = 8 m-tiles (16 rows), full K ---------
  const int lane = tid & 63, wv = tid >> 6;
  const int col = lane & 15, quad = lane >> 4;
  const int m0 = wv * 16 + col;        // A row (batch)
  const int ko = quad * 8;
  const float b1v = bs1[col], b2v = bs2[col];
  const f16* W1f = W1s + lane * 8;
  const f16* W2f = W2s + lane * 8;
  f16* ringw = RING + wv * (NSLOT * 512);
  // per-lane source offset within a window: row (wv*16+col), k-sub quad*8
  const int lane_off = (wv * 16 + col) * H_ + quad * 8;

  f16 *h1c = p.h1a, *h1n = p.h1b, *h2c = p.h2a, *h2n = p.h2b;

  // pointwise + shfl-pack + write-through u64 store of 4 f16
  auto lstm_pw = [&](float* cst, f16* hn) {
    int mm = tid >> 2, cc = tid & 3;
    float gi = Sg[mm * 17 + cc],     gf = Sg[mm * 17 + 4 + cc];
    float gg = Sg[mm * 17 + 8 + cc], go = Sg[mm * 17 + 12 + cc];
    float cn = sigm(gf) * cst[tid] + sigm(gi) * tanh_(gg);
    cst[tid] = cn;
    f16 hv = (f16)(sigm(go) * tanh_(cn));
    int v = (int)__builtin_bit_cast(unsigned short, hv);
    int base = lane & ~3;
    int v0 = __shfl(v, base, 64),     v1 = __shfl(v, base + 1, 64);
    int v2 = __shfl(v, base + 2, 64), v3 = __shfl(v, base + 3, 64);
    if (cc == 0) {
      unsigned long long pk = (unsigned long long)(unsigned short)v0
        | ((unsigned long long)(unsigned short)v1 << 16)
        | ((unsigned long long)(unsigned short)v2 << 32)
        | ((unsigned long long)(unsigned short)v3 << 48);
      __hip_atomic_store((unsigned long long*)(hn + mm * H_ + hb), pk,
                         __ATOMIC_RELAXED, __HIP_MEMORY_SCOPE_AGENT);
    }
  };

  // fused phase: gates1(t+1) [l1] and gates2(t) [l2], both keyed on h1c
  auto phase = [&](bool l1, bool l2, const f16* xp, int xstr) {
    float4v a1 = {b1v, b1v, b1v, b1v};
    float4v a2 = {b2v, b2v, b2v, b2v};
    const int nwin = l2 ? 64 : 32;    // windows: 0..31 h1, 32..63 h2

    // x-part loads (register path) + drain so ring vmcnt accounting is exact
    half8 ax0, ax1;
    if (l1) {
      ax0 = *(const half8*)(xp + m0 * xstr + ko);
      ax1 = *(const half8*)(xp + m0 * xstr + 32 + ko);
    }
    asm volatile("s_waitcnt vmcnt(0)" ::: "memory");

    // preload DMA windows 0..DEPTH-1
    {
      int slot = 0;
      for (int w = 0; w < DEPTH; ++w) {
        const f16* src = (w < 32) ? h1c : h2c;
        stage_dma(src + lane_off + (w & 31) * 32, ringw + slot * 512);
        if (++slot == NSLOT) slot = 0;
      }
    }
    // x MFMAs overlap DMA preload latency
    if (l1) {
      a1 = __builtin_amdgcn_mfma_f32_16x16x32_f16(ax0, *(const half8*)(W1f + 32 * 512), a1, 0, 0, 0);
      a1 = __builtin_amdgcn_mfma_f32_16x16x32_f16(ax1, *(const half8*)(W1f + 33 * 512), a1, 0, 0, 0);
    }

    // land window 0
    WAIT_VM(DEPTH - 1);
    half8 a_cur = *(const half8*)(ringw + lane * 8);
    int slot_i = DEPTH % NSLOT;       // next issue slot (window DEPTH)
    int slot_n = 1;                   // slot of window w+1

    #pragma unroll 4
    for (int w = 0; w < nwin; ++w) {
      int wn = w + DEPTH;
      if (wn < nwin) {
        const f16* src = (wn < 32) ? h1c : h2c;
        stage_dma(src + lane_off + (wn & 31) * 32, ringw + slot_i * 512);
        if (++slot_i == NSLOT) slot_i = 0;
      }
      half8 a_next;
      if (w + 1 < nwin) {
        int rem = nwin - 2 - w;       // outstanding beyond window w+1
        if (rem > DEPTH - 1) rem = DEPTH - 1;
        WAIT_VM(rem);
        a_next = *(const half8*)(ringw + slot_n * 512 + lane * 8);
        if (++slot_n == NSLOT) slot_n = 0;
      }
      if (l1 && w < 32)
        a1 = __builtin_amdgcn_mfma_f32_16x16x32_f16(a_cur, *(const half8*)(W1f + w * 512), a1, 0, 0, 0);
      if (l2)
        a2 = __builtin_amdgcn_mfma_f32_16x16x32_f16(a_cur, *(const half8*)(W2f + w * 512), a2, 0, 0, 0);
      a_cur = a_next;
    }
    asm volatile("s_waitcnt vmcnt(0)" ::: "memory");   // all DMA drained

    // ---- epilogue: transpose via Sg, LSTM pointwise, write-through h ----
    __syncthreads();
    if (l1) {
      #pragma unroll
      for (int r = 0; r < 4; ++r)
        Sg[(wv * 16 + quad * 4 + r) * 17 + col] = a1[r];
    }
    __syncthreads();
    if (l1) lstm_pw(c1, h1n);
    __syncthreads();
    if (l2) {
      #pragma unroll
      for (int r = 0; r < 4; ++r)
        Sg[(wv * 16 + quad * 4 + r) * 17 + col] = a2[r];
    }
    __syncthreads();
    if (l2) lstm_pw(c2, h2n);
  };

  // small projection: out[m][j] = h2 . W[j] + b[j]  (fp32 weights)
  auto out_phase = [&](const float* W, const float* bv, bool wout) {
    int j = bid & 63, mgp = bid >> 6;
    int rid = tid >> 4, ks = tid & 15;
    int mrow = mgp * 32 + rid;
    const f16* hr = h2c + mrow * H_ + ks * 64;
    const float* wr = W + j * H_ + ks * 64;
    float s = 0.f;
    #pragma unroll 8
    for (int k = 0; k < 64; ++k) s += (float)hr[k] * wr[k];
    s += __shfl_down(s, 8, 16);
    s += __shfl_down(s, 4, 16);
    s += __shfl_down(s, 2, 16);
    s += __shfl_down(s, 1, 16);
    if (ks == 0) {
      float v = s + bv[j];
      f16 hv = (f16)v;
      __hip_atomic_store((unsigned short*)&p.ob[mrow * 64 + j],
                         __builtin_bit_cast(unsigned short, hv),
                         __ATOMIC_RELAXED, __HIP_MEMORY_SCOPE_AGENT);
      if (wout) p.out[mrow * 64 + j] = v;
    }
  };

  // ---------------- time loop: 129 fused phases ----------------------------
  for (int t = -1; t < T_; ++t) {
    bool l1 = (t + 1 < T_), l2 = (t >= 0);
    phase(l1, l2, p.x16 + (t + 1) * DIN, T_ * DIN);
    gsync();
    if (l1) { f16* tm = h1c; h1c = h1n; h1n = tm; }
    if (l2) { f16* tm = h2c; h2c = h2n; h2n = tm; }
  }
  out_phase(p.Wlin, p.blin, fut == 0);
  gsync();
  for (int f = 0; f < fut; ++f) {
    phase(true, false, p.ob, 64);
    gsync();
    { f16* tm = h1c; h1c = h1n; h1n = tm; }
    phase(false, true, p.ob, 64);
    gsync();
    { f16* tm = h2c; h2c = h2n; h2n = tm; }
    out_phase(p.Whio, p.bhio, f == fut - 1);
    gsync();
  }
}

extern "C" void kernel_launch(void* const* d_in, const int* in_sizes, int n_in,
                              void* d_out, int out_size, void* d_ws, size_t ws_size,
                              hipStream_t stream) {
  char* w = (char*)d_ws;
  auto carve = [&](size_t n) { char* r = w; w += (n + 255) & ~(size_t)255; return r; };

  Params p;
  p.x    = (const float*)d_in[0];
  p.Wih1 = (const float*)d_in[1];
  p.Whh1 = (const float*)d_in[2];
  p.bih1 = (const float*)d_in[3];
  p.bhh1 = (const float*)d_in[4];
  p.Wih2 = (const float*)d_in[5];
  p.Whh2 = (const float*)d_in[6];
  p.bih2 = (const float*)d_in[7];
  p.bhh2 = (const float*)d_in[8];
  p.Wlin = (const float*)d_in[9];
  p.blin = (const float*)d_in[10];
  p.Whio = (const float*)d_in[11];
  p.bhio = (const float*)d_in[12];
  p.fut  = (const int*)d_in[13];
  p.out  = (float*)d_out;

  p.x16 = (f16*)carve((size_t)B_ * T_ * DIN * 2);
  p.h1a = (f16*)carve((size_t)B_ * H_ * 2);
  p.h1b = (f16*)carve((size_t)B_ * H_ * 2);
  p.h2a = (f16*)carve((size_t)B_ * H_ * 2);
  p.h2b = (f16*)carve((size_t)B_ * H_ * 2);
  p.ob  = (f16*)carve((size_t)B_ * 64 * 2);
  p.arrive = (unsigned*)carve(NBLK * sizeof(unsigned));
  p.rel    = (unsigned*)carve(256);
  p.S      = (unsigned*)carve(64 * sizeof(unsigned));

  (void)hipFuncSetAttribute((const void*)lstm_k,
                            hipFuncAttributeMaxDynamicSharedMemorySize, SMEM_BYTES);
  void* args[] = { &p };
  (void)hipLaunchCooperativeKernel((void*)lstm_k, dim3(NBLK), dim3(NTHR),
                                   args, SMEM_BYTES, stream);
}

// Round 6
// 2608.663 us; speedup vs baseline: 1.1990x; 1.1387x over previous
//
#include <hip/hip_runtime.h>

#define B_   128
#define T_   128
#define DIN  64
#define H_   1024
#define NBLK 256
#define NTHR 512
#define NSLOT 6
#define DEPTH 5

typedef _Float16 f16;
typedef _Float16 half8 __attribute__((ext_vector_type(8)));
typedef float float4v __attribute__((ext_vector_type(4)));

// LDS layout:
//  W1s : f16[34][512]  lane-ordered fragments                34816 B
//  W2s : f16[64][512]                                        65536 B
//  RING: f16[8 waves][6 slots][512]  A-stream DMA ring       49152 B
//  Sg  : float[128][17]                                       8704 B
//  c1,c2: float[512] each                                     4096 B
//  bs1,bs2: float[16] each                                     128 B
#define OFF_W2   34816
#define OFF_RING 100352
#define OFF_SG   149504
#define OFF_C1   158208
#define OFF_C2   160256
#define OFF_B1   162304
#define OFF_B2   162368
#define SMEM_BYTES 162432

// Barrier state S (unsigned[2048], 8 KB), one 128-B line per hot word:
//  S[x*32]        : per-XCD ticket        (x = 0..15)
//  S[512]         : central XCD counter
//  S[544]         : release word          (polled by <=8 XCD leaders)
//  S[576 + x*32]  : per-XCD flag          (polled by <=31 blocks)
//  S[1600 + x]    : per-XCD block count   (preamble only)

struct Params {
  const float *x, *Wih1, *Whh1, *bih1, *bhh1, *Wih2, *Whh2, *bih2, *bhh2,
              *Wlin, *blin, *Whio, *bhio;
  const int* fut;
  float* out;
  f16 *x16, *h1a, *h1b, *h2a, *h2b, *ob;
  unsigned *arrive, *rel;
  unsigned *S;
};

__device__ __forceinline__ float sigm(float v) { return 1.f / (1.f + __expf(-v)); }
__device__ __forceinline__ float tanh_(float v) { return 2.f / (1.f + __expf(-2.f * v)) - 1.f; }

__device__ __forceinline__ unsigned get_xcc() {
  unsigned x;
  asm volatile("s_getreg_b32 %0, hwreg(HW_REG_XCC_ID)" : "=s"(x));
  return x & 15u;
}

// DMA one 32-k window (16 rows x 32 k, fragment-ordered) into an LDS slot.
__device__ __forceinline__ void stage_dma(const f16* src_lane, f16* lds_base) {
  __builtin_amdgcn_global_load_lds(
      (const __attribute__((address_space(1))) void*)src_lane,
      (__attribute__((address_space(3))) void*)lds_base, 16, 0, 0);
}

#define WAIT_VM(n)                                                        \
  do {                                                                    \
    switch (n) {                                                          \
      case 4: asm volatile("s_waitcnt vmcnt(4)" ::: "memory"); break;     \
      case 3: asm volatile("s_waitcnt vmcnt(3)" ::: "memory"); break;     \
      case 2: asm volatile("s_waitcnt vmcnt(2)" ::: "memory"); break;     \
      case 1: asm volatile("s_waitcnt vmcnt(1)" ::: "memory"); break;     \
      default: asm volatile("s_waitcnt vmcnt(0)" ::: "memory"); break;    \
    }                                                                     \
  } while (0)

// ---- slow barrier (preamble only) -----------------------------------------
__device__ __forceinline__ void grid_sync(unsigned* arrive, unsigned* rel, unsigned ph) {
  __syncthreads();
  const int tid = threadIdx.x, bid = blockIdx.x;
  if (bid == 0) {
    if (tid > 0 && tid < NBLK) {
      while (__hip_atomic_load(&arrive[tid], __ATOMIC_RELAXED, __HIP_MEMORY_SCOPE_AGENT) != ph)
        __builtin_amdgcn_s_sleep(8);
    }
    __syncthreads();
    if (tid == 0)
      __hip_atomic_store(rel, ph, __ATOMIC_RELEASE, __HIP_MEMORY_SCOPE_AGENT);
  } else {
    if (tid == 0) {
      __hip_atomic_store(&arrive[bid], ph, __ATOMIC_RELEASE, __HIP_MEMORY_SCOPE_AGENT);
      while (__hip_atomic_load(rel, __ATOMIC_RELAXED, __HIP_MEMORY_SCOPE_AGENT) != ph)
        __builtin_amdgcn_s_sleep(8);
    }
  }
  __syncthreads();
  __builtin_amdgcn_fence(__ATOMIC_ACQUIRE, "agent");
}

// ---- fast barrier v3: line-spread state + hierarchical fan-out.
// <=8 pollers on the release line, <=31 on each per-XCD flag line; backoff
// keeps per-line request rate below the L3 bank service rate (no queueing
// collapse). One buffer_inv sc1 per XCD (leader); others L1-only.
__device__ __forceinline__ void fast_sync(unsigned* S, unsigned x, unsigned xtotal,
                                          unsigned nxcd, unsigned ph) {
  __syncthreads();   // drains vmcnt: h write-through stores at coherence point
  if (threadIdx.x == 0) {
    unsigned t = __hip_atomic_fetch_add(&S[x * 32], 1u, __ATOMIC_RELAXED, __HIP_MEMORY_SCOPE_AGENT);
    bool leader = (t % xtotal == 0u);
    if ((t + 1u) % xtotal == 0u) {            // last block of this XCD
      unsigned c = __hip_atomic_fetch_add(&S[512], 1u, __ATOMIC_RELAXED, __HIP_MEMORY_SCOPE_AGENT);
      if ((c + 1u) % nxcd == 0u)              // last XCD globally -> release
        __hip_atomic_store(&S[544], ph, __ATOMIC_RELAXED, __HIP_MEMORY_SCOPE_AGENT);
    }
    if (leader) {
      while (__hip_atomic_load(&S[544], __ATOMIC_RELAXED, __HIP_MEMORY_SCOPE_AGENT) != ph)
        __builtin_amdgcn_s_sleep(2);
      asm volatile("buffer_inv sc0 sc1\n\ts_waitcnt vmcnt(0)" ::: "memory");
      __hip_atomic_store(&S[576 + x * 32], ph, __ATOMIC_RELAXED, __HIP_MEMORY_SCOPE_AGENT);
    } else {
      while (__hip_atomic_load(&S[576 + x * 32], __ATOMIC_RELAXED, __HIP_MEMORY_SCOPE_AGENT) != ph)
        __builtin_amdgcn_s_sleep(4);
      asm volatile("buffer_inv sc0\n\ts_waitcnt vmcnt(0)" ::: "memory");  // local L1
    }
  }
  __syncthreads();
}

__global__ void __launch_bounds__(NTHR, 1) lstm_k(Params p) {
  extern __shared__ char smem[];
  f16*   W1s  = (f16*)(smem);
  f16*   W2s  = (f16*)(smem + OFF_W2);
  f16*   RING = (f16*)(smem + OFF_RING);
  float* Sg   = (float*)(smem + OFF_SG);
  float* c1   = (float*)(smem + OFF_C1);
  float* c2   = (float*)(smem + OFF_C2);
  float* bs1  = (float*)(smem + OFF_B1);
  float* bs2  = (float*)(smem + OFF_B2);

  const int tid = threadIdx.x, bid = blockIdx.x;
  const int hb  = bid * 4;
  const int fut = p.fut[0];
  const unsigned xcc = get_xcc();
  unsigned* S = p.S;

  if (bid == 0) {
    for (int i = tid; i < 2048; i += NTHR)
      __hip_atomic_store(&S[i], 0u, __ATOMIC_RELAXED, __HIP_MEMORY_SCOPE_AGENT);
  }

  // ---------------- preamble ------------------------------------------------
  for (int idx = tid; idx < 34 * 512; idx += NTHR) {
    int c = idx >> 9, r = idx & 511;
    int q = r >> 7, colw = (r >> 3) & 15, j = r & 7;
    int k = c * 32 + q * 8 + j;
    int row = (colw >> 2) * H_ + hb + (colw & 3);
    float v = (k < H_) ? p.Whh1[row * H_ + k] : p.Wih1[row * DIN + (k - H_)];
    W1s[idx] = (f16)v;
  }
  for (int idx = tid; idx < 64 * 512; idx += NTHR) {
    int c = idx >> 9, r = idx & 511;
    int q = r >> 7, colw = (r >> 3) & 15, j = r & 7;
    int k = c * 32 + q * 8 + j;
    int row = (colw >> 2) * H_ + hb + (colw & 3);
    float v = (k < H_) ? p.Wih2[row * H_ + k] : p.Whh2[row * H_ + (k - H_)];
    W2s[idx] = (f16)v;
  }
  if (tid < 16) {
    int row = (tid >> 2) * H_ + hb + (tid & 3);
    bs1[tid] = p.bih1[row] + p.bhh1[row];
    bs2[tid] = p.bih2[row] + p.bhh2[row];
  }
  for (int i = tid; i < 512; i += NTHR) { c1[i] = 0.f; c2[i] = 0.f; }
  for (int i = bid * NTHR + tid; i < B_ * T_ * DIN; i += NBLK * NTHR)
    p.x16[i] = (f16)p.x[i];
  for (int i = bid * NTHR + tid; i < B_ * H_; i += NBLK * NTHR) {
    p.h1a[i] = (f16)0.f; p.h1b[i] = (f16)0.f;
    p.h2a[i] = (f16)0.f; p.h2b[i] = (f16)0.f;
  }

  unsigned ph = 1;
  grid_sync(p.arrive, p.rel, ph);           // preamble + S-zero visible
  if (tid == 0)
    __hip_atomic_fetch_add(&S[1600 + xcc], 1u, __ATOMIC_RELAXED, __HIP_MEMORY_SCOPE_AGENT);
  ++ph;
  grid_sync(p.arrive, p.rel, ph);           // per-XCD block counts final

  unsigned xtotal = __hip_atomic_load(&S[1600 + xcc], __ATOMIC_RELAXED, __HIP_MEMORY_SCOPE_AGENT);
  unsigned nxcd = 0;
  for (int i = 0; i < 16; ++i)
    nxcd += (__hip_atomic_load(&S[1600 + i], __ATOMIC_RELAXED, __HIP_MEMORY_SCOPE_AGENT) != 0u);

  auto gsync = [&]() { ++ph; fast_sync(S, xcc, xtotal, nxcd, ph); };

  // ---------- wave geometry: 8 waves = 8 m-tiles (16 rows), full K ---------
  const int lane = tid & 63, wv = tid >> 6;
  const int col = lane & 15, quad = lane >> 4;
  const int m0 = wv * 16 + col;        // A row (batch)
  const int ko = quad * 8;
  const float b1v = bs1[col], b2v = bs2[col];
  const f16* W1f = W1s + lane * 8;
  const f16* W2f = W2s + lane * 8;
  f16* ringw = RING + wv * (NSLOT * 512);
  const int lane_off = (wv * 16 + col) * H_ + quad * 8;

  f16 *h1c = p.h1a, *h1n = p.h1b, *h2c = p.h2a, *h2n = p.h2b;

  // pointwise + shfl-pack + write-through u64 store of 4 f16
  auto lstm_pw = [&](float* cst, f16* hn) {
    int mm = tid >> 2, cc = tid & 3;
    float gi = Sg[mm * 17 + cc],     gf = Sg[mm * 17 + 4 + cc];
    float gg = Sg[mm * 17 + 8 + cc], go = Sg[mm * 17 + 12 + cc];
    float cn = sigm(gf) * cst[tid] + sigm(gi) * tanh_(gg);
    cst[tid] = cn;
    f16 hv = (f16)(sigm(go) * tanh_(cn));
    int v = (int)__builtin_bit_cast(unsigned short, hv);
    int base = lane & ~3;
    int v0 = __shfl(v, base, 64),     v1 = __shfl(v, base + 1, 64);
    int v2 = __shfl(v, base + 2, 64), v3 = __shfl(v, base + 3, 64);
    if (cc == 0) {
      unsigned long long pk = (unsigned long long)(unsigned short)v0
        | ((unsigned long long)(unsigned short)v1 << 16)
        | ((unsigned long long)(unsigned short)v2 << 32)
        | ((unsigned long long)(unsigned short)v3 << 48);
      __hip_atomic_store((unsigned long long*)(hn + mm * H_ + hb), pk,
                         __ATOMIC_RELAXED, __HIP_MEMORY_SCOPE_AGENT);
    }
  };

  // fused phase: gates1(t+1) [l1] and gates2(t) [l2], both keyed on h1c
  auto phase = [&](bool l1, bool l2, const f16* xp, int xstr) {
    float4v a1 = {b1v, b1v, b1v, b1v};
    float4v a2 = {b2v, b2v, b2v, b2v};
    const int nwin = l2 ? 64 : 32;    // windows: 0..31 h1, 32..63 h2

    half8 ax0, ax1;
    if (l1) {
      ax0 = *(const half8*)(xp + m0 * xstr + ko);
      ax1 = *(const half8*)(xp + m0 * xstr + 32 + ko);
    }
    asm volatile("s_waitcnt vmcnt(0)" ::: "memory");

    // preload DMA windows 0..DEPTH-1
    {
      int slot = 0;
      for (int w = 0; w < DEPTH; ++w) {
        const f16* src = (w < 32) ? h1c : h2c;
        stage_dma(src + lane_off + (w & 31) * 32, ringw + slot * 512);
        if (++slot == NSLOT) slot = 0;
      }
    }
    if (l1) {
      a1 = __builtin_amdgcn_mfma_f32_16x16x32_f16(ax0, *(const half8*)(W1f + 32 * 512), a1, 0, 0, 0);
      a1 = __builtin_amdgcn_mfma_f32_16x16x32_f16(ax1, *(const half8*)(W1f + 33 * 512), a1, 0, 0, 0);
    }

    WAIT_VM(DEPTH - 1);
    half8 a_cur = *(const half8*)(ringw + lane * 8);
    int slot_i = DEPTH % NSLOT;
    int slot_n = 1;

    #pragma unroll 4
    for (int w = 0; w < nwin; ++w) {
      int wn = w + DEPTH;
      if (wn < nwin) {
        const f16* src = (wn < 32) ? h1c : h2c;
        stage_dma(src + lane_off + (wn & 31) * 32, ringw + slot_i * 512);
        if (++slot_i == NSLOT) slot_i = 0;
      }
      half8 a_next;
      if (w + 1 < nwin) {
        int rem = nwin - 2 - w;
        if (rem > DEPTH - 1) rem = DEPTH - 1;
        WAIT_VM(rem);
        a_next = *(const half8*)(ringw + slot_n * 512 + lane * 8);
        if (++slot_n == NSLOT) slot_n = 0;
      }
      if (l1 && w < 32)
        a1 = __builtin_amdgcn_mfma_f32_16x16x32_f16(a_cur, *(const half8*)(W1f + w * 512), a1, 0, 0, 0);
      if (l2)
        a2 = __builtin_amdgcn_mfma_f32_16x16x32_f16(a_cur, *(const half8*)(W2f + w * 512), a2, 0, 0, 0);
      a_cur = a_next;
    }
    asm volatile("s_waitcnt vmcnt(0)" ::: "memory");

    // ---- epilogue: transpose via Sg, LSTM pointwise, write-through h ----
    __syncthreads();
    if (l1) {
      #pragma unroll
      for (int r = 0; r < 4; ++r)
        Sg[(wv * 16 + quad * 4 + r) * 17 + col] = a1[r];
    }
    __syncthreads();
    if (l1) lstm_pw(c1, h1n);
    __syncthreads();
    if (l2) {
      #pragma unroll
      for (int r = 0; r < 4; ++r)
        Sg[(wv * 16 + quad * 4 + r) * 17 + col] = a2[r];
    }
    __syncthreads();
    if (l2) lstm_pw(c2, h2n);
  };

  // small projection: out[m][j] = h2 . W[j] + b[j]  (fp32 weights)
  auto out_phase = [&](const float* W, const float* bv, bool wout) {
    int j = bid & 63, mgp = bid >> 6;
    int rid = tid >> 4, ks = tid & 15;
    int mrow = mgp * 32 + rid;
    const f16* hr = h2c + mrow * H_ + ks * 64;
    const float* wr = W + j * H_ + ks * 64;
    float s = 0.f;
    #pragma unroll 8
    for (int k = 0; k < 64; ++k) s += (float)hr[k] * wr[k];
    s += __shfl_down(s, 8, 16);
    s += __shfl_down(s, 4, 16);
    s += __shfl_down(s, 2, 16);
    s += __shfl_down(s, 1, 16);
    if (ks == 0) {
      float v = s + bv[j];
      f16 hv = (f16)v;
      __hip_atomic_store((unsigned short*)&p.ob[mrow * 64 + j],
                         __builtin_bit_cast(unsigned short, hv),
                         __ATOMIC_RELAXED, __HIP_MEMORY_SCOPE_AGENT);
      if (wout) p.out[mrow * 64 + j] = v;
    }
  };

  // ---------------- time loop: 129 fused phases ----------------------------
  for (int t = -1; t < T_; ++t) {
    bool l1 = (t + 1 < T_), l2 = (t >= 0);
    phase(l1, l2, p.x16 + (t + 1) * DIN, T_ * DIN);
    gsync();
    if (l1) { f16* tm = h1c; h1c = h1n; h1n = tm; }
    if (l2) { f16* tm = h2c; h2c = h2n; h2n = tm; }
  }
  out_phase(p.Wlin, p.blin, fut == 0);
  gsync();
  for (int f = 0; f < fut; ++f) {
    phase(true, false, p.ob, 64);
    gsync();
    { f16* tm = h1c; h1c = h1n; h1n = tm; }
    phase(false, true, p.ob, 64);
    gsync();
    { f16* tm = h2c; h2c = h2n; h2n = tm; }
    out_phase(p.Whio, p.bhio, f == fut - 1);
    gsync();
  }
}

extern "C" void kernel_launch(void* const* d_in, const int* in_sizes, int n_in,
                              void* d_out, int out_size, void* d_ws, size_t ws_size,
                              hipStream_t stream) {
  char* w = (char*)d_ws;
  auto carve = [&](size_t n) { char* r = w; w += (n + 255) & ~(size_t)255; return r; };

  Params p;
  p.x    = (const float*)d_in[0];
  p.Wih1 = (const float*)d_in[1];
  p.Whh1 = (const float*)d_in[2];
  p.bih1 = (const float*)d_in[3];
  p.bhh1 = (const float*)d_in[4];
  p.Wih2 = (const float*)d_in[5];
  p.Whh2 = (const float*)d_in[6];
  p.bih2 = (const float*)d_in[7];
  p.bhh2 = (const float*)d_in[8];
  p.Wlin = (const float*)d_in[9];
  p.blin = (const float*)d_in[10];
  p.Whio = (const float*)d_in[11];
  p.bhio = (const float*)d_in[12];
  p.fut  = (const int*)d_in[13];
  p.out  = (float*)d_out;

  p.x16 = (f16*)carve((size_t)B_ * T_ * DIN * 2);
  p.h1a = (f16*)carve((size_t)B_ * H_ * 2);
  p.h1b = (f16*)carve((size_t)B_ * H_ * 2);
  p.h2a = (f16*)carve((size_t)B_ * H_ * 2);
  p.h2b = (f16*)carve((size_t)B_ * H_ * 2);
  p.ob  = (f16*)carve((size_t)B_ * 64 * 2);
  p.arrive = (unsigned*)carve(NBLK * sizeof(unsigned));
  p.rel    = (unsigned*)carve(256);
  p.S      = (unsigned*)carve(2048 * sizeof(unsigned));

  (void)hipFuncSetAttribute((const void*)lstm_k,
                            hipFuncAttributeMaxDynamicSharedMemorySize, SMEM_BYTES);
  void* args[] = { &p };
  (void)hipLaunchCooperativeKernel((void*)lstm_k, dim3(NBLK), dim3(NTHR),
                                   args, SMEM_BYTES, stream);
}